// Round 5
// baseline (155.444 us; speedup 1.0000x reference)
//
#include <hip/hip_runtime.h>
#include <hip/hip_fp16.h>

#define TSTEPS 4
#define DIM 32
#define BINW_SHIFT 8          // 256 nodes per coarse bin
#define NB 256                // bins (actual 196, rest zero)
#define SP_CH 2048            // edges per chunk (hist & split use same chunking)
#define PAD_PER_BIN 772       // worst-case rec padding per bin (256*3 + 4)

typedef _Float16 f16x8 __attribute__((ext_vector_type(8)));
typedef float f32x4 __attribute__((ext_vector_type(4)));

// load 8 consecutive halfs (16B, aligned) -> two float4
__device__ __forceinline__ void ldx8h(const __half* p, float4& lo, float4& hi) {
    uint4 u = *(const uint4*)p;
    __half2 h0 = *(__half2*)&u.x;
    __half2 h1 = *(__half2*)&u.y;
    __half2 h2 = *(__half2*)&u.z;
    __half2 h3 = *(__half2*)&u.w;
    float2 a = __half22float2(h0);
    float2 b = __half22float2(h1);
    float2 c = __half22float2(h2);
    float2 d = __half22float2(h3);
    lo = make_float4(a.x, a.y, b.x, b.y);
    hi = make_float4(c.x, c.y, d.x, d.y);
}

// ---- K1: per-chunk coarse histogram (blocks [0,nchunks)) + MFMA GEMM ----
__global__ __launch_bounds__(256) void histgemm_kernel(
    const int* __restrict__ ei, int* __restrict__ ghist,
    const float* __restrict__ s, const float* __restrict__ W,
    __half* __restrict__ xwp, int E, int rows, int N, int nchunks) {
    __shared__ float Wf[32][33];   // 4.2 KB; hist role reuses first 1 KB
    int tid = threadIdx.x;

    if ((int)blockIdx.x < nchunks) {
        int* lh = (int*)Wf;
        lh[tid] = 0;
        __syncthreads();
        int beg = blockIdx.x * SP_CH;
        int end = min(beg + SP_CH, E);
        for (int e = beg + tid; e < end; e += 256)
            atomicAdd(&lh[ei[E + e] >> BINW_SHIFT], 1);
        __syncthreads();
        ghist[(size_t)blockIdx.x * NB + tid] = lh[tid];
        return;
    }

    // ---- GEMM role ----
    {
        float4 wv = ((const float4*)W)[tid];
        int kk = tid >> 3, c4 = (tid & 7) * 4;
        Wf[kk][c4 + 0] = wv.x; Wf[kk][c4 + 1] = wv.y;
        Wf[kk][c4 + 2] = wv.z; Wf[kk][c4 + 3] = wv.w;
    }
    __syncthreads();

    int lane = tid & 63;
    int wid  = tid >> 6;          // 0..3
    int lrow = lane & 15;         // A-row / B-col / D-col fragment index
    int kq   = lane >> 4;         // k-group 0..3
    int k0   = kq * 8;

    f16x8 b0, b1;
#pragma unroll
    for (int i = 0; i < 8; i++) {
        b0[i] = (_Float16)Wf[k0 + i][lrow];
        b1[i] = (_Float16)Wf[k0 + i][lrow + 16];
    }

    int rbase = ((int)blockIdx.x - nchunks) * 128 + wid * 32;
#pragma unroll
    for (int rt = 0; rt < 2; rt++) {
        int r = rbase + rt * 16 + lrow;
        f16x8 a;
        if (r < rows) {
            const float4* sp = (const float4*)(s + (size_t)r * 32 + k0);
            float4 u0 = sp[0], u1 = sp[1];
            a[0] = (_Float16)u0.x; a[1] = (_Float16)u0.y;
            a[2] = (_Float16)u0.z; a[3] = (_Float16)u0.w;
            a[4] = (_Float16)u1.x; a[5] = (_Float16)u1.y;
            a[6] = (_Float16)u1.z; a[7] = (_Float16)u1.w;
        } else {
#pragma unroll
            for (int i = 0; i < 8; i++) a[i] = (_Float16)0.f;
        }
        f32x4 c0 = {0.f, 0.f, 0.f, 0.f};
        f32x4 c1 = {0.f, 0.f, 0.f, 0.f};
        c0 = __builtin_amdgcn_mfma_f32_16x16x32_f16(a, b0, c0, 0, 0, 0);
        c1 = __builtin_amdgcn_mfma_f32_16x16x32_f16(a, b1, c1, 0, 0, 0);
        int rr = rbase + rt * 16 + kq * 4;
#pragma unroll
        for (int reg = 0; reg < 4; reg++) {
            int r2 = rr + reg;
            if (r2 < rows) {
                int t = (r2 >= 3 * N) ? 3 : (r2 >= 2 * N) ? 2 : (r2 >= N) ? 1 : 0;
                int n = r2 - t * N;
                __half* dst = xwp + (size_t)n * 128 + t * 32;
                dst[lrow]      = __float2half(c0[reg]);
                dst[lrow + 16] = __float2half(c1[reg]);
            }
        }
    }
}

// ---- K2: transposed scan over chunks per bin ----
__global__ __launch_bounds__(512) void colscan_kernel(
    const int* __restrict__ ghist, int* __restrict__ ghist2,
    int* __restrict__ totals, int nchunks) {
    __shared__ int sc[512];
    int t = threadIdx.x;
    int b = blockIdx.x;
    int v = (t < nchunks) ? ghist[(size_t)t * NB + b] : 0;
    sc[t] = v;
    __syncthreads();
    for (int off = 1; off < 512; off <<= 1) {
        int tv = (t >= off) ? sc[t - off] : 0;
        __syncthreads();
        sc[t] += tv;
        __syncthreads();
    }
    if (t < nchunks) ghist2[(size_t)t * NB + b] = sc[t] - v;   // exclusive
    if (t == 511) totals[b] = sc[511];
}

// ---- K3: split with exact precomputed bases ----
__global__ __launch_bounds__(256) void split_kernel(
    const int* __restrict__ ei, const int* __restrict__ ghist,
    const int* __restrict__ ghist2, const int* __restrict__ totals,
    unsigned int* __restrict__ esorted, int E) {
    __shared__ int binB[NB], pscan[NB], gb[NB], pcur[NB];
    __shared__ unsigned int sbuf[SP_CH];
    int tid = threadIdx.x;
    int bid = blockIdx.x;

    int tot = totals[tid];
    binB[tid] = tot;
    __syncthreads();
    for (int off = 1; off < 256; off <<= 1) {
        int t = (tid >= off) ? binB[tid - off] : 0;
        __syncthreads();
        binB[tid] += t;
        __syncthreads();
    }
    int v = ghist[(size_t)bid * NB + tid];
    pscan[tid] = v;
    __syncthreads();
    for (int off = 1; off < 256; off <<= 1) {
        int t = (tid >= off) ? pscan[tid - off] : 0;
        __syncthreads();
        pscan[tid] += t;
        __syncthreads();
    }
    int pexcl = pscan[tid] - v;
    pscan[tid] = pexcl;
    pcur[tid] = pexcl;
    gb[tid] = (binB[tid] - tot) + ghist2[(size_t)bid * NB + tid] - pexcl;
    __syncthreads();

    int beg = bid * SP_CH;
    int end = min(beg + SP_CH, E);
    int cnt = end - beg;
    for (int e = beg + tid; e < end; e += 256) {
        int sx = ei[e];
        int dx = ei[E + e];
        unsigned int pk = (unsigned int)sx | ((unsigned int)dx << 16);
        int b = dx >> BINW_SHIFT;
        int p = atomicAdd(&pcur[b], 1);
        sbuf[p] = pk;
    }
    __syncthreads();
    for (int idx = tid; idx < cnt; idx += 256) {
        unsigned int e = sbuf[idx];
        int b = e >> 24;                 // dst>>8 (dst in bits 16..31)
        esorted[gb[b] + idx] = e;
    }
}

// ---- K4: per-bin exact CSR ----
__global__ __launch_bounds__(256) void csr_kernel(
    const int* __restrict__ totals, const unsigned int* __restrict__ esorted,
    int* __restrict__ rec, int* __restrict__ offs, int* __restrict__ deg,
    float* __restrict__ dinv, int N) {
    __shared__ int lh[NB], sc[NB], loff[NB], lcur[NB];
    __shared__ int s_ebeg, s_cnt;
    int bin = blockIdx.x;
    int tid = threadIdx.x;
    sc[tid] = totals[tid];
    lh[tid] = 0;
    __syncthreads();
    for (int off = 1; off < 256; off <<= 1) {
        int t = (tid >= off) ? sc[tid - off] : 0;
        __syncthreads();
        sc[tid] += t;
        __syncthreads();
    }
    if (tid == 0) {
        int e0 = bin ? sc[bin - 1] : 0;
        s_ebeg = e0;
        s_cnt = sc[bin] - e0;
    }
    __syncthreads();
    int ebeg = s_ebeg;
    int cnt = s_cnt;
    int gbase = ((ebeg + 3) & ~3) + PAD_PER_BIN * bin;
    for (int i = tid; i < cnt; i += 256)
        atomicAdd(&lh[(esorted[ebeg + i] >> 16) & 255], 1);
    __syncthreads();
    int padded = (lh[tid] + 3) & ~3;
    sc[tid] = padded;
    __syncthreads();
    for (int off = 1; off < 256; off <<= 1) {
        int t = (tid >= off) ? sc[tid - off] : 0;
        __syncthreads();
        sc[tid] += t;
        __syncthreads();
    }
    loff[tid] = sc[tid] - padded;
    lcur[tid] = 0;
    __syncthreads();
    for (int i = tid; i < cnt; i += 256) {
        unsigned int e = esorted[ebeg + i];
        int ln = (e >> 16) & 255;
        int p = atomicAdd(&lcur[ln], 1);
        rec[gbase + loff[ln] + p] = (int)(e & 0xFFFFu);
    }
    int n = (bin << BINW_SHIFT) + tid;
    if (n < N) {
        offs[n] = gbase + loff[tid];
        deg[n] = lh[tid];
        dinv[n] = rsqrtf((float)lh[tid] + 1.0f);
    }
}

// ---- K5: fused gather, 16 lanes/node x dwordx4 (halved VMEM instr count),
// + self-loop + mean + IF + z_new. Lane l holds halfs [l*8, l*8+8). ----
__global__ __launch_bounds__(256) void gather_kernel(
    const int* __restrict__ rec, const int* __restrict__ offs,
    const int* __restrict__ deg, const __half* __restrict__ xwp,
    const float* __restrict__ dinv, const float* __restrict__ z,
    float* __restrict__ out, int N) {
    int gid = blockIdx.x * 256 + threadIdx.x;
    int n = gid >> 4;
    if (n >= N) return;
    int wl = threadIdx.x & 63;
    int g = wl >> 4;          // node slot in wave (0..3)
    int l = wl & 15;          // lane within node
    long lofs = (long)l * 8;  // offset in halfs (16B per lane)

    float dn = dinv[n];
    int beg = offs[n];        // multiple of 4 -> int4-aligned
    int cntn = deg[n];

    float4 aLo = make_float4(0.f, 0.f, 0.f, 0.f);
    float4 aHi = make_float4(0.f, 0.f, 0.f, 0.f);
    int i = 0;
    for (; i + 8 <= cntn; i += 8) {
        int4 sa = *(const int4*)(rec + beg + i);
        int4 sb = *(const int4*)(rec + beg + i + 4);
        float n0 = dinv[sa.x] * dn, n1 = dinv[sa.y] * dn;
        float n2 = dinv[sa.z] * dn, n3 = dinv[sa.w] * dn;
        float n4 = dinv[sb.x] * dn, n5 = dinv[sb.y] * dn;
        float n6 = dinv[sb.z] * dn, n7 = dinv[sb.w] * dn;
        float4 l0, h0, l1, h1, l2, h2, l3, h3;
        float4 l4, h4, l5, h5, l6, h6, l7, h7;
        ldx8h(xwp + (long)sa.x * 128 + lofs, l0, h0);
        ldx8h(xwp + (long)sa.y * 128 + lofs, l1, h1);
        ldx8h(xwp + (long)sa.z * 128 + lofs, l2, h2);
        ldx8h(xwp + (long)sa.w * 128 + lofs, l3, h3);
        ldx8h(xwp + (long)sb.x * 128 + lofs, l4, h4);
        ldx8h(xwp + (long)sb.y * 128 + lofs, l5, h5);
        ldx8h(xwp + (long)sb.z * 128 + lofs, l6, h6);
        ldx8h(xwp + (long)sb.w * 128 + lofs, l7, h7);
        aLo.x += n0*l0.x + n1*l1.x + n2*l2.x + n3*l3.x + n4*l4.x + n5*l5.x + n6*l6.x + n7*l7.x;
        aLo.y += n0*l0.y + n1*l1.y + n2*l2.y + n3*l3.y + n4*l4.y + n5*l5.y + n6*l6.y + n7*l7.y;
        aLo.z += n0*l0.z + n1*l1.z + n2*l2.z + n3*l3.z + n4*l4.z + n5*l5.z + n6*l6.z + n7*l7.z;
        aLo.w += n0*l0.w + n1*l1.w + n2*l2.w + n3*l3.w + n4*l4.w + n5*l5.w + n6*l6.w + n7*l7.w;
        aHi.x += n0*h0.x + n1*h1.x + n2*h2.x + n3*h3.x + n4*h4.x + n5*h5.x + n6*h6.x + n7*h7.x;
        aHi.y += n0*h0.y + n1*h1.y + n2*h2.y + n3*h3.y + n4*h4.y + n5*h5.y + n6*h6.y + n7*h7.y;
        aHi.z += n0*h0.z + n1*h1.z + n2*h2.z + n3*h3.z + n4*h4.z + n5*h5.z + n6*h6.z + n7*h7.z;
        aHi.w += n0*h0.w + n1*h1.w + n2*h2.w + n3*h3.w + n4*h4.w + n5*h5.w + n6*h6.w + n7*h7.w;
    }
    for (; i < cntn; i += 4) {
        int4 s4 = *(const int4*)(rec + beg + i);
        int rem = cntn - i;
        int i0 = s4.x;
        int i1 = (rem > 1) ? s4.y : i0;
        int i2 = (rem > 2) ? s4.z : i0;
        int i3 = (rem > 3) ? s4.w : i0;
        float n0 = dinv[i0] * dn;
        float n1 = (rem > 1) ? dinv[i1] * dn : 0.f;
        float n2 = (rem > 2) ? dinv[i2] * dn : 0.f;
        float n3 = (rem > 3) ? dinv[i3] * dn : 0.f;
        float4 l0, h0, l1, h1, l2, h2, l3, h3;
        ldx8h(xwp + (long)i0 * 128 + lofs, l0, h0);
        ldx8h(xwp + (long)i1 * 128 + lofs, l1, h1);
        ldx8h(xwp + (long)i2 * 128 + lofs, l2, h2);
        ldx8h(xwp + (long)i3 * 128 + lofs, l3, h3);
        aLo.x += n0*l0.x + n1*l1.x + n2*l2.x + n3*l3.x;
        aLo.y += n0*l0.y + n1*l1.y + n2*l2.y + n3*l3.y;
        aLo.z += n0*l0.z + n1*l1.z + n2*l2.z + n3*l3.z;
        aLo.w += n0*l0.w + n1*l1.w + n2*l2.w + n3*l3.w;
        aHi.x += n0*h0.x + n1*h1.x + n2*h2.x + n3*h3.x;
        aHi.y += n0*h0.y + n1*h1.y + n2*h2.y + n3*h3.y;
        aHi.z += n0*h0.z + n1*h1.z + n2*h2.z + n3*h3.z;
        aHi.w += n0*h0.w + n1*h1.w + n2*h2.w + n3*h3.w;
    }
    // self loop
    {
        float d2 = dn * dn;
        float4 sl, sh;
        ldx8h(xwp + (long)n * 128 + lofs, sl, sh);
        aLo.x += d2 * sl.x; aLo.y += d2 * sl.y; aLo.z += d2 * sl.z; aLo.w += d2 * sl.w;
        aHi.x += d2 * sh.x; aHi.y += d2 * sh.y; aHi.z += d2 * sh.z; aHi.w += d2 * sh.w;
    }
    // Lane l holds halfs l*8..l*8+7 (t = l>>2, feature block (l&3)*8).
    // Epilogue lane l<4 owns features f = l*8..l*8+7; x_t(f) lives at lane
    // base + t*4 + l, element j = f&7.
    float a8[8] = {aLo.x, aLo.y, aLo.z, aLo.w, aHi.x, aHi.y, aHi.z, aHi.w};
    float xs[TSTEPS][8];
    int base = g * 16;
#pragma unroll
    for (int t = 0; t < TSTEPS; t++) {
        int srcLane = base + t * 4 + l;
#pragma unroll
        for (int j = 0; j < 8; j++)
            xs[t][j] = __shfl(a8[j], srcLane, 64);
    }
    if (l < 4) {
        int colBase = n * 32 + l * 8;
        float v[8], y[8];
#pragma unroll
        for (int j = 0; j < 8; j++) {
            v[j] = 0.f;
            y[j] = (xs[0][j] + xs[1][j] + xs[2][j] + xs[3][j]) * 0.25f;
        }
#pragma unroll
        for (int t = 0; t < TSTEPS; t++) {
            float o[8];
#pragma unroll
            for (int j = 0; j < 8; j++) {
                v[j] += xs[t][j];
                o[j] = (v[j] >= 1.0f) ? 1.0f : 0.0f;
                v[j] -= o[j];
            }
            float* dst = out + (size_t)t * N * 32 + colBase;
            *(float4*)dst       = make_float4(o[0], o[1], o[2], o[3]);
            *(float4*)(dst + 4) = make_float4(o[4], o[5], o[6], o[7]);
        }
        float4 zv0 = *(const float4*)(z + colBase);
        float4 zv1 = *(const float4*)(z + colBase + 4);
        float* dst = out + (size_t)TSTEPS * N * 32 + colBase;
        *(float4*)dst       = make_float4(zv0.x + y[0], zv0.y + y[1], zv0.z + y[2], zv0.w + y[3]);
        *(float4*)(dst + 4) = make_float4(zv1.x + y[4], zv1.y + y[5], zv1.z + y[6], zv1.w + y[7]);
    }
}

extern "C" void kernel_launch(void* const* d_in, const int* in_sizes, int n_in,
                              void* d_out, int out_size, void* d_ws, size_t ws_size,
                              hipStream_t stream) {
    const float* s_seq = (const float*)d_in[0];
    const float* z_seq = (const float*)d_in[1];
    const float* W     = (const float*)d_in[2];
    const int*   ei    = (const int*)d_in[3];
    float* out = (float*)d_out;

    int N = in_sizes[1] / DIM;   // 50000
    int E = in_sizes[3] / 2;     // 800000
    int rows = TSTEPS * N;       // 200000
    int nb = (N + 255) >> BINW_SHIFT;        // 196
    int nchunks = (E + SP_CH - 1) / SP_CH;   // 391

    char* w = (char*)d_ws;
    __half* xwp           = (__half*)w;       w += (size_t)rows * DIM * 2;   // 12.8 MB
    unsigned int* esorted = (unsigned int*)w; w += (size_t)E * 4;            // 3.2 MB
    int*   rec    = (int*)w;  w += ((size_t)E + PAD_PER_BIN * nb + 16) * 4;  // 3.8 MB
    int*   offs   = (int*)w;  w += (size_t)N * 4;
    int*   deg    = (int*)w;  w += (size_t)N * 4;
    float* dinv   = (float*)w; w += (size_t)N * 4;
    int*   ghist  = (int*)w;  w += (size_t)nchunks * NB * 4;                 // 400 KB
    int*   ghist2 = (int*)w;  w += (size_t)nchunks * NB * 4;                 // 400 KB
    int*   totals = (int*)w;  w += NB * 4;

    int xwBlocks = (rows + 127) / 128;   // 1563
    histgemm_kernel<<<nchunks + xwBlocks, 256, 0, stream>>>(
        ei, ghist, s_seq, W, xwp, E, rows, N, nchunks);
    colscan_kernel<<<NB, 512, 0, stream>>>(ghist, ghist2, totals, nchunks);
    split_kernel<<<nchunks, 256, 0, stream>>>(ei, ghist, ghist2, totals, esorted, E);
    csr_kernel<<<nb, 256, 0, stream>>>(totals, esorted, rec, offs, deg, dinv, N);
    gather_kernel<<<(N * 16 + 255) / 256, 256, 0, stream>>>(rec, offs, deg, xwp,
                                                            dinv, z_seq, out, N);
}